// Round 5
// baseline (86.815 us; speedup 1.0000x reference)
//
#include <hip/hip_runtime.h>
#include <math.h>

#define BATCH 8
#define NBOX 10000
#define NQ4 2500            // NBOX/4
#define NCLS 80
#define KSEL 8
#define MAXT 8
#define IOU_THR 0.5f
#define SCORE_THR 0.5f
#define NEGV -1000000000.0f
#define TILE_N 64

// ---------------------------------------------------------------------------
// Transpose + threshold: (B,N,C) -> (B*C, N). Coalesced on BOTH global sides.
// (unchanged from R4 — measured ~HBM-bound)
// ---------------------------------------------------------------------------
__global__ __launch_bounds__(256) void transpose_scores(
    const float* __restrict__ scores, float* __restrict__ st)
{
    __shared__ float tile[NCLS][TILE_N + 1];   // 80 x 65 floats = 20.8 KB
    const int b   = blockIdx.y;
    const int n0  = blockIdx.x * TILE_N;
    const int tid = threadIdx.x;
    const int nrem = min(TILE_N, NBOX - n0);   // 64, or 16 for the last block
    const float4* src = (const float4*)(scores + (size_t)b * NBOX * NCLS
                                               + (size_t)n0 * NCLS);
    if (nrem == TILE_N) {
        #pragma unroll
        for (int k = 0; k < 5; ++k) {
            int i = tid + k * 256;             // 1280 float4 = 64 boxes x 20
            float4 v = src[i];
            int nl = i / 20, c4 = i - nl * 20;
            tile[c4 * 4 + 0][nl] = (v.x > SCORE_THR) ? v.x : NEGV;
            tile[c4 * 4 + 1][nl] = (v.y > SCORE_THR) ? v.y : NEGV;
            tile[c4 * 4 + 2][nl] = (v.z > SCORE_THR) ? v.z : NEGV;
            tile[c4 * 4 + 3][nl] = (v.w > SCORE_THR) ? v.w : NEGV;
        }
        __syncthreads();
        #pragma unroll
        for (int k = 0; k < 5; ++k) {
            int j = tid + k * 256;             // 1280 float4 = 80 c x 16 n4
            int c = j >> 4, n4 = j & 15;
            float4 o;
            o.x = tile[c][n4 * 4 + 0];
            o.y = tile[c][n4 * 4 + 1];
            o.z = tile[c][n4 * 4 + 2];
            o.w = tile[c][n4 * 4 + 3];
            *(float4*)&st[((size_t)b * NCLS + c) * NBOX + n0 + n4 * 4] = o;
        }
    } else {
        for (int i = tid; i < nrem * (NCLS / 4); i += 256) {
            float4 v = src[i];
            int nl = i / 20, c4 = i - nl * 20;
            tile[c4 * 4 + 0][nl] = (v.x > SCORE_THR) ? v.x : NEGV;
            tile[c4 * 4 + 1][nl] = (v.y > SCORE_THR) ? v.y : NEGV;
            tile[c4 * 4 + 2][nl] = (v.z > SCORE_THR) ? v.z : NEGV;
            tile[c4 * 4 + 3][nl] = (v.w > SCORE_THR) ? v.w : NEGV;
        }
        __syncthreads();
        const int nq = nrem >> 2;
        for (int j = tid; j < nq * NCLS; j += 256) {
            int c = j / nq, n4 = j - c * nq;
            float4 o;
            o.x = tile[c][n4 * 4 + 0];
            o.y = tile[c][n4 * 4 + 1];
            o.z = tile[c][n4 * 4 + 2];
            o.w = tile[c][n4 * 4 + 3];
            *(float4*)&st[((size_t)b * NCLS + c) * NBOX + n0 + n4 * 4] = o;
        }
    }
}

// IoU of candidate cb (area carea) vs kept box KB (area KA); per-op IEEE
// rounding identical to numpy reference; union order = kept_area + cand_area.
#define IOU_SUP(KB, KA)                                                     \
    do {                                                                    \
        float ih = fmaxf(__fsub_rn(fminf((KB).z, cb.z), fmaxf((KB).x, cb.x)), 0.0f); \
        float iw = fmaxf(__fsub_rn(fminf((KB).w, cb.w), fmaxf((KB).y, cb.y)), 0.0f); \
        float inter = __fmul_rn(ih, iw);                                    \
        float uni   = __fsub_rn(__fadd_rn((KA), carea), inter);             \
        float iou   = __fdiv_rn(inter, fmaxf(uni, 1e-9f));                  \
        if (iou > IOU_THR) sup = true;                                      \
    } while (0)

// top-2 update, first-index tie-break (process in ascending n)
#define TOP2_UPD(X, N)                                                      \
    do {                                                                    \
        if ((X) > mv1)      { mv2 = mv1; mi2 = mi1; mv1 = (X); mi1 = (N); } \
        else if ((X) > mv2) { mv2 = (X); mi2 = (N); }                       \
    } while (0)

// ---------------------------------------------------------------------------
// One WAVE (64 lanes) per (b,c). No LDS, no __syncthreads. Lane l owns
// float4 chunks m = a*64 + l (n = 4m+q); keeps running top-2 + removal
// bitmask (160 bits). Per extraction round: shfl_xor butterfly argmax,
// IoU vs kept boxes in named registers, owner promotes/rescans.
// ---------------------------------------------------------------------------
__global__ __launch_bounds__(64) void nms_extract_wave(
    const float* __restrict__ st,       // (B*C, N) thresholded, or nullptr
    const float* __restrict__ scores,   // raw (B,N,C) fallback
    const float* __restrict__ boxes,    // (B,N,4)
    float* __restrict__ ws_msc,
    float4* __restrict__ ws_box,
    int use_t)
{
    const int bid = blockIdx.x;
    const int b   = bid & 7;            // batch -> XCD pin (heuristic)
    const int c   = bid >> 3;
    const int bc  = b * NCLS + c;
    const int l   = threadIdx.x;

    const float4* row4 = (const float4*)(st + (size_t)bc * NBOX);
    const float*  raw  = scores + (size_t)b * NBOX * NCLS + c;
    const float4* box4 = (const float4*)(boxes + (size_t)b * NBOX * 4);

    float mv1 = NEGV, mv2 = NEGV;
    int   mi1 = 0,    mi2 = 0;
    bool  v2ok = true;
    unsigned long long rm0 = 0, rm1 = 0, rm2 = 0;   // removed bits, e = 4a+q

    // ---- streaming pass: coalesced loads + in-register top-2 ----
    if (use_t) {
        #pragma unroll
        for (int a = 0; a < 40; ++a) {
            const int m = a * 64 + l;
            float4 v;
            if (m < NQ4) v = row4[m];               // a<39: always true
            else v = make_float4(NEGV, NEGV, NEGV, NEGV);
            const int n = 4 * m;
            TOP2_UPD(v.x, n);
            TOP2_UPD(v.y, n + 1);
            TOP2_UPD(v.z, n + 2);
            TOP2_UPD(v.w, n + 3);
        }
    } else {
        #pragma unroll
        for (int a = 0; a < 40; ++a) {
            #pragma unroll
            for (int q = 0; q < 4; ++q) {
                const int n = 4 * (a * 64 + l) + q;
                float x = (n < NBOX) ? raw[(size_t)n * NCLS] : NEGV;
                x = (x > SCORE_THR) ? x : NEGV;
                TOP2_UPD(x, n);
            }
        }
    }

    // kept boxes in named registers (uniform values across lanes)
    float4 kb0, kb1, kb2, kb3, kb4, kb5, kb6, kb7;
    float  ka0 = 0, ka1 = 0, ka2 = 0, ka3 = 0, ka4 = 0, ka5 = 0, ka6 = 0, ka7 = 0;
    kb0 = kb1 = kb2 = kb3 = kb4 = kb5 = kb6 = kb7 = make_float4(0, 0, 0, 0);

    int kept = 0;
    for (;;) {
        // ---- wave argmax (butterfly: all lanes converge), first-index ties
        float bv = mv1; int bi = mi1;
        #pragma unroll
        for (int off = 1; off < 64; off <<= 1) {
            float ov = __shfl_xor(bv, off, 64);
            int   oi = __shfl_xor(bi, off, 64);
            if (ov > bv || (ov == bv && oi < bi)) { bv = ov; bi = oi; }
        }
        if (!(bv > SCORE_THR)) break;

        const float4 cb = box4[bi];         // uniform address
        const float carea = __fmul_rn(__fsub_rn(cb.z, cb.x), __fsub_rn(cb.w, cb.y));

        bool sup = false;
        if (kept > 0) IOU_SUP(kb0, ka0);
        if (kept > 1) IOU_SUP(kb1, ka1);
        if (kept > 2) IOU_SUP(kb2, ka2);
        if (kept > 3) IOU_SUP(kb3, ka3);
        if (kept > 4) IOU_SUP(kb4, ka4);
        if (kept > 5) IOU_SUP(kb5, ka5);
        if (kept > 6) IOU_SUP(kb6, ka6);
        if (kept > 7) IOU_SUP(kb7, ka7);

        if (!sup) {
            if (l == 0) {
                int o = bc * KSEL + kept;
                ws_msc[o] = bv;
                ws_box[o] = cb;
            }
            if      (kept == 0) { kb0 = cb; ka0 = carea; }
            else if (kept == 1) { kb1 = cb; ka1 = carea; }
            else if (kept == 2) { kb2 = cb; ka2 = carea; }
            else if (kept == 3) { kb3 = cb; ka3 = carea; }
            else if (kept == 4) { kb4 = cb; ka4 = carea; }
            else if (kept == 5) { kb5 = cb; ka5 = carea; }
            else if (kept == 6) { kb6 = cb; ka6 = carea; }
            else                { kb7 = cb; ka7 = carea; }
            kept++;
        }

        // ---- removal: owner lane only (winner == owner's mv1)
        if (((bi >> 2) & 63) == l) {
            const int e = ((bi >> 8) << 2) | (bi & 3);   // 4a + q, < 160
            if (e < 64)       rm0 |= 1ull << e;
            else if (e < 128) rm1 |= 1ull << (e - 64);
            else              rm2 |= 1ull << (e - 128);
            if (v2ok) {
                mv1 = mv2; mi1 = mi2; v2ok = false;
            } else {
                // full rescan of this lane's values, skipping removed bits
                mv1 = NEGV; mi1 = 0; mv2 = NEGV; mi2 = 0;
                for (int a = 0; a < 40; ++a) {
                    const int m = a * 64 + l;
                    if (m >= NQ4) break;
                    float x0, x1, x2, x3;
                    if (use_t) {
                        float4 v = row4[m];
                        x0 = v.x; x1 = v.y; x2 = v.z; x3 = v.w;
                    } else {
                        const int n = 4 * m;
                        x0 = raw[(size_t)(n + 0) * NCLS];
                        x1 = raw[(size_t)(n + 1) * NCLS];
                        x2 = raw[(size_t)(n + 2) * NCLS];
                        x3 = raw[(size_t)(n + 3) * NCLS];
                        x0 = (x0 > SCORE_THR) ? x0 : NEGV;
                        x1 = (x1 > SCORE_THR) ? x1 : NEGV;
                        x2 = (x2 > SCORE_THR) ? x2 : NEGV;
                        x3 = (x3 > SCORE_THR) ? x3 : NEGV;
                    }
                    const int e0 = a * 4;
                    unsigned long long mask =
                        (e0 < 64) ? (rm0 >> e0)
                      : (e0 < 128) ? (rm1 >> (e0 - 64))
                                   : (rm2 >> (e0 - 128));
                    if (mask & 1) x0 = NEGV;
                    if (mask & 2) x1 = NEGV;
                    if (mask & 4) x2 = NEGV;
                    if (mask & 8) x3 = NEGV;
                    const int n = 4 * m;
                    TOP2_UPD(x0, n);
                    TOP2_UPD(x1, n + 1);
                    TOP2_UPD(x2, n + 2);
                    TOP2_UPD(x3, n + 3);
                }
                v2ok = true;
            }
        }
        if (kept == MAXT) break;
    }

    if (l == 0) {
        for (int k = kept; k < MAXT; ++k) {
            int o = bc * KSEL + k;
            ws_msc[o] = NEGV;
            ws_box[o] = make_float4(0.f, 0.f, 0.f, 0.f);
        }
    }
}

// ---------------------------------------------------------------------------
// One block per batch: register-resident stable top-MAXT over C*K = 640 slots.
// (unchanged from R4)
// ---------------------------------------------------------------------------
__global__ __launch_bounds__(256) void topk_combine(
    const float* __restrict__ ws_msc,
    const float4* __restrict__ ws_box,
    float* __restrict__ out)
{
    __shared__ float red_val[2][4];
    __shared__ int   red_idx[2][4];

    const int b = blockIdx.x;
    const int tid = threadIdx.x;
    const float* msc = ws_msc + b * NCLS * KSEL;

    float v0 = (tid       < NCLS * KSEL) ? msc[tid]       : -INFINITY;
    float v1 = (tid + 256 < NCLS * KSEL) ? msc[tid + 256] : -INFINITY;
    float v2 = (tid + 512 < NCLS * KSEL) ? msc[tid + 512] : -INFINITY;

    const int OFF_SC = BATCH * MAXT * 4;
    const int OFF_CL = OFF_SC + BATCH * MAXT;
    const int OFF_VD = OFF_CL + BATCH * MAXT;

    int cnt = 0;
    int p = 0;
    #pragma unroll
    for (int t = 0; t < MAXT; ++t) {
        float bv = v0; int bi = tid;
        if (v1 > bv) { bv = v1; bi = tid + 256; }   // ascending i -> first max
        if (v2 > bv) { bv = v2; bi = tid + 512; }
        #pragma unroll
        for (int off = 32; off > 0; off >>= 1) {
            float ov = __shfl_down(bv, off, 64);
            int   oi = __shfl_down(bi, off, 64);
            if (ov > bv || (ov == bv && oi < bi)) { bv = ov; bi = oi; }
        }
        if ((tid & 63) == 0) { red_val[p][tid >> 6] = bv; red_idx[p][tid >> 6] = bi; }
        __syncthreads();
        bv = red_val[p][0]; bi = red_idx[p][0];
        #pragma unroll
        for (int w = 1; w < 4; ++w) {
            float ov = red_val[p][w]; int oi = red_idx[p][w];
            if (ov > bv || (ov == bv && oi < bi)) { bv = ov; bi = oi; }
        }
        p ^= 1;

        const bool valid = bv > SCORE_THR;
        cnt += valid ? 1 : 0;
        if (tid == t) {
            float4 bx = ws_box[b * NCLS * KSEL + bi];
            float* ob = out + ((size_t)b * MAXT + t) * 4;
            ob[0] = valid ? fminf(fmaxf(bx.x, 0.0f), 1.0f) : 0.0f;
            ob[1] = valid ? fminf(fmaxf(bx.y, 0.0f), 1.0f) : 0.0f;
            ob[2] = valid ? fminf(fmaxf(bx.z, 0.0f), 1.0f) : 0.0f;
            ob[3] = valid ? fminf(fmaxf(bx.w, 0.0f), 1.0f) : 0.0f;
            out[OFF_SC + b * MAXT + t] = valid ? bv : 0.0f;
            out[OFF_CL + b * MAXT + t] = valid ? (float)(bi >> 3) : 0.0f;
        }
        if (tid == (bi & 255)) {
            int w = bi >> 8;
            if (w == 0) v0 = -INFINITY;
            else if (w == 1) v1 = -INFINITY;
            else v2 = -INFINITY;
        }
    }
    if (tid == 0) out[OFF_VD + b] = (float)cnt;
}

extern "C" void kernel_launch(void* const* d_in, const int* in_sizes, int n_in,
                              void* d_out, int out_size, void* d_ws, size_t ws_size,
                              hipStream_t stream) {
    const float* boxes  = (const float*)d_in[0];   // (B, N, 1, 4)
    const float* scores = (const float*)d_in[1];   // (B, N, C)
    float* out = (float*)d_out;

    const size_t t_bytes   = (size_t)BATCH * NCLS * NBOX * sizeof(float); // 25.6 MB
    const size_t msc_bytes = (size_t)BATCH * NCLS * KSEL * sizeof(float);
    const size_t box_bytes = (size_t)BATCH * NCLS * KSEL * sizeof(float4);

    int use_t = (ws_size >= t_bytes + msc_bytes + box_bytes) ? 1 : 0;

    float* st; float* ws_msc; float4* ws_box;
    if (use_t) {
        st     = (float*)d_ws;
        ws_msc = (float*)((char*)d_ws + t_bytes);
        ws_box = (float4*)((char*)d_ws + t_bytes + msc_bytes);
    } else {
        st     = nullptr;
        ws_msc = (float*)d_ws;
        ws_box = (float4*)((char*)d_ws + msc_bytes);
    }

    if (use_t) {
        dim3 tg((NBOX + TILE_N - 1) / TILE_N, BATCH);
        transpose_scores<<<tg, 256, 0, stream>>>(scores, st);
    }
    nms_extract_wave<<<BATCH * NCLS, 64, 0, stream>>>(st, scores, boxes,
                                                      ws_msc, ws_box, use_t);
    topk_combine<<<BATCH, 256, 0, stream>>>(ws_msc, ws_box, out);
}

// Round 6
// 59.261 us; speedup vs baseline: 1.4650x; 1.4650x over previous
//
#include <hip/hip_runtime.h>
#include <math.h>

#define BATCH 8
#define NBOX 10000
#define NQ4 2500            // NBOX/4
#define NCLS 80
#define KSEL 8
#define MAXT 8
#define IOU_THR 0.5f
#define SCORE_THR 0.5f
#define NEGV -1000000000.0f
#define TILE_N 64
#define CHK4 128            // float4 per chunk (512 floats, = 1<<9)
#define NCHK 20             // chunks per class (20*512 = 10240 >= 10000)
#define HEADS 40            // NCHK * 2
#define IDXINF 0x7fffffff

// global candidate order: (val desc, idx asc) — matches jnp.argmax ties
__device__ __forceinline__ bool beats(float av, int an, float bv, int bn) {
    return (av > bv) || (av == bv && an < bn);
}

// ---------------------------------------------------------------------------
// Transpose + threshold: (B,N,C) -> (B*C, N). Coalesced on BOTH global sides.
// (unchanged from R4 — measured ~HBM-bound)
// ---------------------------------------------------------------------------
__global__ __launch_bounds__(256) void transpose_scores(
    const float* __restrict__ scores, float* __restrict__ st)
{
    __shared__ float tile[NCLS][TILE_N + 1];   // 80 x 65 floats = 20.8 KB
    const int b   = blockIdx.y;
    const int n0  = blockIdx.x * TILE_N;
    const int tid = threadIdx.x;
    const int nrem = min(TILE_N, NBOX - n0);   // 64, or 16 for the last block
    const float4* src = (const float4*)(scores + (size_t)b * NBOX * NCLS
                                               + (size_t)n0 * NCLS);
    if (nrem == TILE_N) {
        #pragma unroll
        for (int k = 0; k < 5; ++k) {
            int i = tid + k * 256;             // 1280 float4 = 64 boxes x 20
            float4 v = src[i];
            int nl = i / 20, c4 = i - nl * 20;
            tile[c4 * 4 + 0][nl] = (v.x > SCORE_THR) ? v.x : NEGV;
            tile[c4 * 4 + 1][nl] = (v.y > SCORE_THR) ? v.y : NEGV;
            tile[c4 * 4 + 2][nl] = (v.z > SCORE_THR) ? v.z : NEGV;
            tile[c4 * 4 + 3][nl] = (v.w > SCORE_THR) ? v.w : NEGV;
        }
        __syncthreads();
        #pragma unroll
        for (int k = 0; k < 5; ++k) {
            int j = tid + k * 256;             // 1280 float4 = 80 c x 16 n4
            int c = j >> 4, n4 = j & 15;
            float4 o;
            o.x = tile[c][n4 * 4 + 0];
            o.y = tile[c][n4 * 4 + 1];
            o.z = tile[c][n4 * 4 + 2];
            o.w = tile[c][n4 * 4 + 3];
            *(float4*)&st[((size_t)b * NCLS + c) * NBOX + n0 + n4 * 4] = o;
        }
    } else {
        for (int i = tid; i < nrem * (NCLS / 4); i += 256) {
            float4 v = src[i];
            int nl = i / 20, c4 = i - nl * 20;
            tile[c4 * 4 + 0][nl] = (v.x > SCORE_THR) ? v.x : NEGV;
            tile[c4 * 4 + 1][nl] = (v.y > SCORE_THR) ? v.y : NEGV;
            tile[c4 * 4 + 2][nl] = (v.z > SCORE_THR) ? v.z : NEGV;
            tile[c4 * 4 + 3][nl] = (v.w > SCORE_THR) ? v.w : NEGV;
        }
        __syncthreads();
        const int nq = nrem >> 2;
        for (int j = tid; j < nq * NCLS; j += 256) {
            int c = j / nq, n4 = j - c * nq;
            float4 o;
            o.x = tile[c][n4 * 4 + 0];
            o.y = tile[c][n4 * 4 + 1];
            o.z = tile[c][n4 * 4 + 2];
            o.w = tile[c][n4 * 4 + 3];
            *(float4*)&st[((size_t)b * NCLS + c) * NBOX + n0 + n4 * 4] = o;
        }
    }
}

// IoU of candidate cb (area carea) vs kept box KB (area KA); per-op IEEE
// rounding identical to numpy; union order = kept_area + cand_area.
#define IOU_SUP(KB, KA)                                                     \
    do {                                                                    \
        float ih = fmaxf(__fsub_rn(fminf((KB).z, cb.z), fmaxf((KB).x, cb.x)), 0.0f); \
        float iw = fmaxf(__fsub_rn(fminf((KB).w, cb.w), fmaxf((KB).y, cb.y)), 0.0f); \
        float inter = __fmul_rn(ih, iw);                                    \
        float uni   = __fsub_rn(__fadd_rn((KA), carea), inter);             \
        float iou   = __fdiv_rn(inter, fmaxf(uni, 1e-9f));                  \
        if (iou > IOU_THR) sup = true;                                      \
    } while (0)

// top-2 update; values processed in ascending n, so strict > keeps first-idx
#define T2U(X, N)                                                           \
    do {                                                                    \
        if ((X) > h1v)      { h2v = h1v; h2n = h1n; h1v = (X); h1n = (N); } \
        else if ((X) > h2v) { h2v = (X); h2n = (N); }                       \
    } while (0)

// rescan eligibility: strictly below floor (xv,xi) in (val desc, idx asc)
#define ELG(X, N)                                                           \
    do {                                                                    \
        if (((X) < xv || ((X) == xv && (N) > xi)) &&                        \
            ((X) > nv || ((X) == nv && (N) < nn))) { nv = (X); nn = (N); }  \
    } while (0)

#define RAWLD(DST, M, Q)                                                    \
    do { float _t = raw[(size_t)(4 * (M) + (Q)) * NCLS];                    \
         (DST) = (_t > SCORE_THR) ? _t : NEGV; } while (0)

// ---------------------------------------------------------------------------
// One 256-thread block per (b,c).
// Phase 1 (4 waves): top-2 heads of 20 chunks (512 floats each) -> LDS.
// Phase 2 (wave 0): barrier-free NMS rounds over 40 heads; exact lazy
// rescan of a chunk when its blind floor could beat the live max.
// ---------------------------------------------------------------------------
__global__ __launch_bounds__(256) void nms_extract(
    const float* __restrict__ st,       // (B*C, N) thresholded, or nullptr
    const float* __restrict__ scores,   // raw (B,N,C) fallback
    const float* __restrict__ boxes,    // (B,N,4)
    float* __restrict__ ws_msc,
    float4* __restrict__ ws_box,
    int use_t)
{
    __shared__ float hv[HEADS];
    __shared__ int   hn[HEADS];

    const int bid = blockIdx.x;
    const int b   = bid & 7;            // batch -> XCD pin
    const int c   = bid >> 3;
    const int bc  = b * NCLS + c;
    const int tid = threadIdx.x;
    const int l   = tid & 63;
    const int w   = tid >> 6;

    const float4* row4 = (const float4*)(st + (size_t)bc * NBOX);
    const float*  raw  = scores + (size_t)b * NBOX * NCLS + c;
    const float4* box4 = (const float4*)(boxes + (size_t)b * NBOX * 4);

    // ---- phase 1: wave w -> chunks 5w..5w+4 ----
    float4 va[5], vb[5];
    if (use_t) {
        #pragma unroll
        for (int j = 0; j < 5; ++j) {
            const int m0 = (w * 5 + j) * CHK4 + l;   // <= 2495, always valid
            const int m1 = m0 + 64;
            va[j] = row4[m0];
            vb[j] = (m1 < NQ4) ? row4[m1]
                               : make_float4(NEGV, NEGV, NEGV, NEGV);
        }
    } else {
        #pragma unroll
        for (int j = 0; j < 5; ++j) {
            const int m0 = (w * 5 + j) * CHK4 + l;
            const int m1 = m0 + 64;
            float4 x, y;
            RAWLD(x.x, m0, 0); RAWLD(x.y, m0, 1);
            RAWLD(x.z, m0, 2); RAWLD(x.w, m0, 3);
            if (m1 < NQ4) {
                RAWLD(y.x, m1, 0); RAWLD(y.y, m1, 1);
                RAWLD(y.z, m1, 2); RAWLD(y.w, m1, 3);
            } else y = make_float4(NEGV, NEGV, NEGV, NEGV);
            va[j] = x; vb[j] = y;
        }
    }
    #pragma unroll
    for (int j = 0; j < 5; ++j) {
        const int ch = w * 5 + j;
        const int m0 = ch * CHK4 + l;
        const int m1 = m0 + 64;
        float h1v = NEGV, h2v = NEGV;
        int   h1n = IDXINF, h2n = IDXINF;
        const float4 v0 = va[j], v1 = vb[j];
        T2U(v0.x, 4*m0+0); T2U(v0.y, 4*m0+1); T2U(v0.z, 4*m0+2); T2U(v0.w, 4*m0+3);
        T2U(v1.x, 4*m1+0); T2U(v1.y, 4*m1+1); T2U(v1.z, 4*m1+2); T2U(v1.w, 4*m1+3);
        // 6-stage sorted-pair allreduce merge -> every lane: chunk top-2
        #pragma unroll
        for (int off = 1; off < 64; off <<= 1) {
            float o1v = __shfl_xor(h1v, off, 64);
            int   o1n = __shfl_xor(h1n, off, 64);
            float o2v = __shfl_xor(h2v, off, 64);
            int   o2n = __shfl_xor(h2n, off, 64);
            const bool bt = beats(h1v, h1n, o1v, o1n);
            const float f1v = bt ? h1v : o1v; const int f1n = bt ? h1n : o1n;
            const float lsv = bt ? o1v : h1v; const int lsn = bt ? o1n : h1n;
            const float wsv = bt ? h2v : o2v; const int wsn = bt ? h2n : o2n;
            const bool bt2 = beats(wsv, wsn, lsv, lsn);
            h1v = f1v; h1n = f1n;
            h2v = bt2 ? wsv : lsv; h2n = bt2 ? wsn : lsn;
        }
        if (l == 0) {
            hv[2*ch]   = h1v; hn[2*ch]   = h1n;
            hv[2*ch+1] = h2v; hn[2*ch+1] = h2n;
        }
    }
    __syncthreads();
    if (w != 0) return;

    // ---- phase 2: wave 0, barrier-free rounds ----
    float cv = (l < HEADS) ? hv[l] : NEGV;
    int   cn = (l < HEADS) ? hn[l] : IDXINF;
    bool  dead = (l >= HEADS);
    float fl_v = NEGV; int fl_i = IDXINF;
    const int mych = l >> 1;

    float4 kb0, kb1, kb2, kb3, kb4, kb5, kb6, kb7;
    float  ka0=0, ka1=0, ka2=0, ka3=0, ka4=0, ka5=0, ka6=0, ka7=0;
    kb0 = kb1 = kb2 = kb3 = kb4 = kb5 = kb6 = kb7 = make_float4(0, 0, 0, 0);
    int kept = 0;

    for (;;) {
        // live argmax over heads
        float bv = dead ? NEGV : cv;
        int   bi = dead ? IDXINF : cn;
        #pragma unroll
        for (int off = 1; off < 64; off <<= 1) {
            float ov = __shfl_xor(bv, off, 64);
            int   oi = __shfl_xor(bi, off, 64);
            if (beats(ov, oi, bv, bi)) { bv = ov; bi = oi; }
        }
        // blind-chunk floors (both heads consumed)
        const unsigned long long db = __ballot(dead);
        const bool blind = (l < HEADS) && (((db >> (2 * mych)) & 3ull) == 3ull);
        float xv = blind ? fl_v : NEGV;
        int   xi = blind ? fl_i : IDXINF;
        #pragma unroll
        for (int off = 1; off < 64; off <<= 1) {
            float ov = __shfl_xor(xv, off, 64);
            int   oi = __shfl_xor(xi, off, 64);
            if (beats(ov, oi, xv, xi)) { xv = ov; xi = oi; }
        }
        if (beats(xv, xi, bv, bi)) {
            // exact rescan of chunk xi>>9: max strictly below floor (xv,xi)
            const int chr = xi >> 9;
            const int m0 = chr * CHK4 + l;
            const int m1 = m0 + 64;
            float4 u0, u1;
            if (use_t) {
                u0 = row4[m0];
                u1 = (m1 < NQ4) ? row4[m1]
                                : make_float4(NEGV, NEGV, NEGV, NEGV);
            } else {
                RAWLD(u0.x, m0, 0); RAWLD(u0.y, m0, 1);
                RAWLD(u0.z, m0, 2); RAWLD(u0.w, m0, 3);
                if (m1 < NQ4) {
                    RAWLD(u1.x, m1, 0); RAWLD(u1.y, m1, 1);
                    RAWLD(u1.z, m1, 2); RAWLD(u1.w, m1, 3);
                } else u1 = make_float4(NEGV, NEGV, NEGV, NEGV);
            }
            float nv = NEGV; int nn = IDXINF;
            ELG(u0.x, 4*m0+0); ELG(u0.y, 4*m0+1); ELG(u0.z, 4*m0+2); ELG(u0.w, 4*m0+3);
            ELG(u1.x, 4*m1+0); ELG(u1.y, 4*m1+1); ELG(u1.z, 4*m1+2); ELG(u1.w, 4*m1+3);
            #pragma unroll
            for (int off = 1; off < 64; off <<= 1) {
                float ov = __shfl_xor(nv, off, 64);
                int   oi = __shfl_xor(nn, off, 64);
                if (beats(ov, oi, nv, nn)) { nv = ov; nn = oi; }
            }
            if (l == 2 * chr) { cv = nv; cn = nn; dead = false; }
            continue;
        }
        if (!(bv > SCORE_THR)) break;

        const float4 cb = box4[bi];         // uniform address
        const float carea = __fmul_rn(__fsub_rn(cb.z, cb.x), __fsub_rn(cb.w, cb.y));

        bool sup = false;
        if (kept > 0) IOU_SUP(kb0, ka0);
        if (kept > 1) IOU_SUP(kb1, ka1);
        if (kept > 2) IOU_SUP(kb2, ka2);
        if (kept > 3) IOU_SUP(kb3, ka3);
        if (kept > 4) IOU_SUP(kb4, ka4);
        if (kept > 5) IOU_SUP(kb5, ka5);
        if (kept > 6) IOU_SUP(kb6, ka6);
        if (kept > 7) IOU_SUP(kb7, ka7);

        if (!sup) {
            if (l == 0) {
                int o = bc * KSEL + kept;
                ws_msc[o] = bv;
                ws_box[o] = cb;
            }
            if      (kept == 0) { kb0 = cb; ka0 = carea; }
            else if (kept == 1) { kb1 = cb; ka1 = carea; }
            else if (kept == 2) { kb2 = cb; ka2 = carea; }
            else if (kept == 3) { kb3 = cb; ka3 = carea; }
            else if (kept == 4) { kb4 = cb; ka4 = carea; }
            else if (kept == 5) { kb5 = cb; ka5 = carea; }
            else if (kept == 6) { kb6 = cb; ka6 = carea; }
            else                { kb7 = cb; ka7 = carea; }
            kept++;
        }

        // consume: owner head dies; its chunk's floor = consumed (bv,bi)
        if (!dead && cn == bi) dead = true;
        if (l < HEADS && (bi >> 9) == mych) { fl_v = bv; fl_i = bi; }
        if (kept == MAXT) break;
    }

    if (l == 0) {
        for (int k = kept; k < MAXT; ++k) {
            int o = bc * KSEL + k;
            ws_msc[o] = NEGV;
            ws_box[o] = make_float4(0.f, 0.f, 0.f, 0.f);
        }
    }
}

// ---------------------------------------------------------------------------
// One block per batch: register-resident stable top-MAXT over C*K = 640 slots.
// (unchanged from R4)
// ---------------------------------------------------------------------------
__global__ __launch_bounds__(256) void topk_combine(
    const float* __restrict__ ws_msc,
    const float4* __restrict__ ws_box,
    float* __restrict__ out)
{
    __shared__ float red_val[2][4];
    __shared__ int   red_idx[2][4];

    const int b = blockIdx.x;
    const int tid = threadIdx.x;
    const float* msc = ws_msc + b * NCLS * KSEL;

    float v0 = (tid       < NCLS * KSEL) ? msc[tid]       : -INFINITY;
    float v1 = (tid + 256 < NCLS * KSEL) ? msc[tid + 256] : -INFINITY;
    float v2 = (tid + 512 < NCLS * KSEL) ? msc[tid + 512] : -INFINITY;

    const int OFF_SC = BATCH * MAXT * 4;
    const int OFF_CL = OFF_SC + BATCH * MAXT;
    const int OFF_VD = OFF_CL + BATCH * MAXT;

    int cnt = 0;
    int p = 0;
    #pragma unroll
    for (int t = 0; t < MAXT; ++t) {
        float bv = v0; int bi = tid;
        if (v1 > bv) { bv = v1; bi = tid + 256; }   // ascending i -> first max
        if (v2 > bv) { bv = v2; bi = tid + 512; }
        #pragma unroll
        for (int off = 32; off > 0; off >>= 1) {
            float ov = __shfl_down(bv, off, 64);
            int   oi = __shfl_down(bi, off, 64);
            if (ov > bv || (ov == bv && oi < bi)) { bv = ov; bi = oi; }
        }
        if ((tid & 63) == 0) { red_val[p][tid >> 6] = bv; red_idx[p][tid >> 6] = bi; }
        __syncthreads();
        bv = red_val[p][0]; bi = red_idx[p][0];
        #pragma unroll
        for (int w = 1; w < 4; ++w) {
            float ov = red_val[p][w]; int oi = red_idx[p][w];
            if (ov > bv || (ov == bv && oi < bi)) { bv = ov; bi = oi; }
        }
        p ^= 1;

        const bool valid = bv > SCORE_THR;
        cnt += valid ? 1 : 0;
        if (tid == t) {
            float4 bx = ws_box[b * NCLS * KSEL + bi];
            float* ob = out + ((size_t)b * MAXT + t) * 4;
            ob[0] = valid ? fminf(fmaxf(bx.x, 0.0f), 1.0f) : 0.0f;
            ob[1] = valid ? fminf(fmaxf(bx.y, 0.0f), 1.0f) : 0.0f;
            ob[2] = valid ? fminf(fmaxf(bx.z, 0.0f), 1.0f) : 0.0f;
            ob[3] = valid ? fminf(fmaxf(bx.w, 0.0f), 1.0f) : 0.0f;
            out[OFF_SC + b * MAXT + t] = valid ? bv : 0.0f;
            out[OFF_CL + b * MAXT + t] = valid ? (float)(bi >> 3) : 0.0f;
        }
        if (tid == (bi & 255)) {
            int w = bi >> 8;
            if (w == 0) v0 = -INFINITY;
            else if (w == 1) v1 = -INFINITY;
            else v2 = -INFINITY;
        }
    }
    if (tid == 0) out[OFF_VD + b] = (float)cnt;
}

extern "C" void kernel_launch(void* const* d_in, const int* in_sizes, int n_in,
                              void* d_out, int out_size, void* d_ws, size_t ws_size,
                              hipStream_t stream) {
    const float* boxes  = (const float*)d_in[0];   // (B, N, 1, 4)
    const float* scores = (const float*)d_in[1];   // (B, N, C)
    float* out = (float*)d_out;

    const size_t t_bytes   = (size_t)BATCH * NCLS * NBOX * sizeof(float); // 25.6 MB
    const size_t msc_bytes = (size_t)BATCH * NCLS * KSEL * sizeof(float);
    const size_t box_bytes = (size_t)BATCH * NCLS * KSEL * sizeof(float4);

    int use_t = (ws_size >= t_bytes + msc_bytes + box_bytes) ? 1 : 0;

    float* st; float* ws_msc; float4* ws_box;
    if (use_t) {
        st     = (float*)d_ws;
        ws_msc = (float*)((char*)d_ws + t_bytes);
        ws_box = (float4*)((char*)d_ws + t_bytes + msc_bytes);
    } else {
        st     = nullptr;
        ws_msc = (float*)d_ws;
        ws_box = (float4*)((char*)d_ws + msc_bytes);
    }

    if (use_t) {
        dim3 tg((NBOX + TILE_N - 1) / TILE_N, BATCH);
        transpose_scores<<<tg, 256, 0, stream>>>(scores, st);
    }
    nms_extract<<<BATCH * NCLS, 256, 0, stream>>>(st, scores, boxes,
                                                  ws_msc, ws_box, use_t);
    topk_combine<<<BATCH, 256, 0, stream>>>(ws_msc, ws_box, out);
}

// Round 7
// 54.964 us; speedup vs baseline: 1.5795x; 1.0782x over previous
//
#include <hip/hip_runtime.h>
#include <math.h>

#define BATCH 8
#define NBOX 10000
#define NCLS 80
#define KSEL 8
#define MAXT 8
#define IOU_THR 0.5f
#define SCORE_THR 0.5f
#define NEGV -1000000000.0f
#define IDXINF 0x7fffffff

#define SUBROWS 256         // rows per class_heads block
#define NSUB 40             // sub-chunks: 40*256 = 10240 >= 10000
#define NCHK 20             // phase-2 chunks of 512 rows (= 2 sub-chunks)
#define HEADS 40            // NCHK * 2 head lanes

// global candidate order: (val desc, idx asc) — matches jnp.argmax ties
__device__ __forceinline__ bool beats(float av, int an, float bv, int bn) {
    return (av > bv) || (av == bv && an < bn);
}

// threshold + top-2 update with named registers (ascending n -> first-idx ties)
#define T2C(V1, I1, V2, I2, X, N)                                           \
    do {                                                                    \
        float _x = ((X) > SCORE_THR) ? (X) : NEGV;                          \
        if (_x > (V1)) { (V2)=(V1); (I2)=(I1); (V1)=_x; (I1)=(N); }         \
        else if (_x > (V2)) { (V2)=_x; (I2)=(N); }                          \
    } while (0)

// merge sorted pair (A1>=A2) into running sorted (h1,j1)>=(h2,j2)
#define MRG(A1, A1N, A2, A2N)                                               \
    do {                                                                    \
        if (beats((A1), (A1N), h1, j1)) {                                   \
            float _t = h1; int _tn = j1;                                    \
            h1 = (A1); j1 = (A1N);                                          \
            if (beats((A2), (A2N), _t, _tn)) { h2 = (A2); j2 = (A2N); }     \
            else                             { h2 = _t;  j2 = _tn;  }       \
        } else if (beats((A1), (A1N), h2, j2)) { h2 = (A1); j2 = (A1N); }   \
    } while (0)

// IoU suppression test, per-op IEEE rounding identical to numpy reference;
// union order = kept_area + cand_area.
#define IOU_SUP(KB, KA)                                                     \
    do {                                                                    \
        float ih = fmaxf(__fsub_rn(fminf((KB).z, cb.z), fmaxf((KB).x, cb.x)), 0.0f); \
        float iw = fmaxf(__fsub_rn(fminf((KB).w, cb.w), fmaxf((KB).y, cb.y)), 0.0f); \
        float inter = __fmul_rn(ih, iw);                                    \
        float uni   = __fsub_rn(__fadd_rn((KA), carea), inter);             \
        float iou   = __fdiv_rn(inter, fmaxf(uni, 1e-9f));                  \
        if (iou > IOU_THR) sup = true;                                      \
    } while (0)

// rescan eligibility: strictly below floor (xv,xi); keep max in beats-order
#define ELG(X, N)                                                           \
    do {                                                                    \
        if (((X) < xv || ((X) == xv && (N) > xi)) &&                        \
            ((X) > nv || ((X) == nv && (N) < nn))) { nv = (X); nn = (N); }  \
    } while (0)

// ---------------------------------------------------------------------------
// Kernel A: per-(batch, 256-row sub-chunk) top-2 heads for all 80 classes.
// Reads raw (B,N,C) ONCE, coalesced float4 across classes. 320 threads:
// thread = (q, g): classes 4q..4q+3, rows g*16..g*16+15 of the sub-chunk.
// ---------------------------------------------------------------------------
__global__ __launch_bounds__(320) void class_heads(
    const float* __restrict__ scores,   // (B, N, C)
    float* __restrict__ hv_g,           // (B*C, 2*NSUB)
    int*   __restrict__ hn_g)
{
    __shared__ float lv[16][NCLS][2];   // 10.2 KB
    __shared__ int   ln[16][NCLS][2];   // 10.2 KB

    const int bid = blockIdx.x;         // b + 8*sub -> XCD pin
    const int b   = bid & 7;
    const int sub = bid >> 3;
    const int n0  = sub * SUBROWS;
    const int tid = threadIdx.x;
    const int q   = tid % 20;           // class quad
    const int g   = tid / 20;           // row group [0,16)

    const float* base = scores + ((size_t)b * NBOX + n0) * NCLS + 4 * q;

    float v10 = NEGV, v20 = NEGV, v11 = NEGV, v21 = NEGV;
    float v12 = NEGV, v22 = NEGV, v13 = NEGV, v23 = NEGV;
    int   i10 = IDXINF, i20 = IDXINF, i11 = IDXINF, i21 = IDXINF;
    int   i12 = IDXINF, i22 = IDXINF, i13 = IDXINF, i23 = IDXINF;

    #pragma unroll 4
    for (int k = 0; k < 16; ++k) {
        const int r = g * 16 + k;
        const int n = n0 + r;
        if (n < NBOX) {
            float4 x = *(const float4*)(base + (size_t)r * NCLS);
            T2C(v10, i10, v20, i20, x.x, n);
            T2C(v11, i11, v21, i21, x.y, n);
            T2C(v12, i12, v22, i22, x.z, n);
            T2C(v13, i13, v23, i23, x.w, n);
        }
    }

    const int c0 = 4 * q;
    lv[g][c0 + 0][0] = v10; lv[g][c0 + 0][1] = v20;
    lv[g][c0 + 1][0] = v11; lv[g][c0 + 1][1] = v21;
    lv[g][c0 + 2][0] = v12; lv[g][c0 + 2][1] = v22;
    lv[g][c0 + 3][0] = v13; lv[g][c0 + 3][1] = v23;
    ln[g][c0 + 0][0] = i10; ln[g][c0 + 0][1] = i20;
    ln[g][c0 + 1][0] = i11; ln[g][c0 + 1][1] = i21;
    ln[g][c0 + 2][0] = i12; ln[g][c0 + 2][1] = i22;
    ln[g][c0 + 3][0] = i13; ln[g][c0 + 3][1] = i23;
    __syncthreads();

    if (tid < NCLS) {
        const int c = tid;
        float h1 = NEGV, h2 = NEGV;
        int   j1 = IDXINF, j2 = IDXINF;
        #pragma unroll
        for (int g2 = 0; g2 < 16; ++g2) {    // ascending g2 = ascending n
            float a1 = lv[g2][c][0], a2 = lv[g2][c][1];
            int  a1n = ln[g2][c][0], a2n = ln[g2][c][1];
            MRG(a1, a1n, a2, a2n);
        }
        const size_t o = ((size_t)(b * NCLS + c)) * (2 * NSUB) + 2 * sub;
        hv_g[o] = h1; hv_g[o + 1] = h2;
        hn_g[o] = j1; hn_g[o + 1] = j2;
    }
}

// ---------------------------------------------------------------------------
// Kernel B: one WAVE per class (4 waves/block, independent; no LDS, no sync).
// Lane l<40 merges two sub-pair heads -> head l of chunk l>>1. Rounds:
// butterfly argmax, IoU vs kept boxes in named registers, blind-floor +
// exact rescan of a 512-row chunk from the raw layout (L2-resident).
// ---------------------------------------------------------------------------
__global__ __launch_bounds__(256) void nms_extract(
    const float* __restrict__ hv_g,
    const int*   __restrict__ hn_g,
    const float* __restrict__ scores,   // raw (B,N,C)
    const float* __restrict__ boxes,    // (B,N,4)
    float* __restrict__ ws_msc,
    float4* __restrict__ ws_box)
{
    const int bid = blockIdx.x;         // b + 8*grp -> XCD pin
    const int b   = bid & 7;
    const int grp = bid >> 3;
    const int w   = threadIdx.x >> 6;
    const int l   = threadIdx.x & 63;
    const int c   = grp * 4 + w;
    const int bc  = b * NCLS + c;

    const float*  raw  = scores + (size_t)b * NBOX * NCLS + c;
    const float4* box4 = (const float4*)(boxes + (size_t)b * NBOX * 4);

    // ---- load + merge heads: chunk ch = l>>1, entries 4*ch..4*ch+3 ----
    float cv = NEGV; int cn = IDXINF;
    bool dead = (l >= HEADS);
    if (l < HEADS) {
        const int ch = l >> 1;
        float4 av = *(const float4*)(hv_g + (size_t)bc * (2 * NSUB) + 4 * ch);
        int4   an = *(const int4*)  (hn_g + (size_t)bc * (2 * NSUB) + 4 * ch);
        float h1 = av.x, h2 = av.y;     // sub 2ch sorted pair
        int   j1 = an.x, j2 = an.y;
        MRG(av.z, an.z, av.w, an.w);    // merge sub 2ch+1
        cv = (l & 1) ? h2 : h1;
        cn = (l & 1) ? j2 : j1;
    }
    float fl_v = NEGV; int fl_i = IDXINF;
    const int mych = l >> 1;

    float4 kb0, kb1, kb2, kb3, kb4, kb5, kb6, kb7;
    float  ka0=0, ka1=0, ka2=0, ka3=0, ka4=0, ka5=0, ka6=0, ka7=0;
    kb0 = kb1 = kb2 = kb3 = kb4 = kb5 = kb6 = kb7 = make_float4(0, 0, 0, 0);
    int kept = 0;

    for (;;) {
        // live argmax over heads
        float bv = dead ? NEGV : cv;
        int   bi = dead ? IDXINF : cn;
        #pragma unroll
        for (int off = 1; off < 64; off <<= 1) {
            float ov = __shfl_xor(bv, off, 64);
            int   oi = __shfl_xor(bi, off, 64);
            if (beats(ov, oi, bv, bi)) { bv = ov; bi = oi; }
        }
        // blind-chunk floors (both heads of a chunk consumed)
        const unsigned long long db = __ballot(dead);
        const bool blind = (l < HEADS) && (((db >> (2 * mych)) & 3ull) == 3ull);
        float xv = blind ? fl_v : NEGV;
        int   xi = blind ? fl_i : IDXINF;
        #pragma unroll
        for (int off = 1; off < 64; off <<= 1) {
            float ov = __shfl_xor(xv, off, 64);
            int   oi = __shfl_xor(xi, off, 64);
            if (beats(ov, oi, xv, xi)) { xv = ov; xi = oi; }
        }
        if (beats(xv, xi, bv, bi)) {
            // exact rescan of chunk xi>>9: max strictly below floor (xv,xi)
            const int chr = xi >> 9;
            const int nb  = chr << 9;
            float nv = NEGV; int nn = IDXINF;
            #pragma unroll
            for (int qq = 0; qq < 8; ++qq) {
                const int n = nb + qq * 64 + l;
                float x = NEGV;
                if (n < NBOX) {
                    float t = raw[(size_t)n * NCLS];
                    x = (t > SCORE_THR) ? t : NEGV;
                }
                ELG(x, n);
            }
            #pragma unroll
            for (int off = 1; off < 64; off <<= 1) {
                float ov = __shfl_xor(nv, off, 64);
                int   oi = __shfl_xor(nn, off, 64);
                if (beats(ov, oi, nv, nn)) { nv = ov; nn = oi; }
            }
            if (l == 2 * chr) { cv = nv; cn = nn; dead = false; }
            continue;
        }
        if (!(bv > SCORE_THR)) break;

        const float4 cb = box4[bi];     // uniform address -> broadcast load
        const float carea = __fmul_rn(__fsub_rn(cb.z, cb.x), __fsub_rn(cb.w, cb.y));

        bool sup = false;
        if (kept > 0) IOU_SUP(kb0, ka0);
        if (kept > 1) IOU_SUP(kb1, ka1);
        if (kept > 2) IOU_SUP(kb2, ka2);
        if (kept > 3) IOU_SUP(kb3, ka3);
        if (kept > 4) IOU_SUP(kb4, ka4);
        if (kept > 5) IOU_SUP(kb5, ka5);
        if (kept > 6) IOU_SUP(kb6, ka6);
        if (kept > 7) IOU_SUP(kb7, ka7);

        if (!sup) {
            if (l == 0) {
                int o = bc * KSEL + kept;
                ws_msc[o] = bv;
                ws_box[o] = cb;
            }
            if      (kept == 0) { kb0 = cb; ka0 = carea; }
            else if (kept == 1) { kb1 = cb; ka1 = carea; }
            else if (kept == 2) { kb2 = cb; ka2 = carea; }
            else if (kept == 3) { kb3 = cb; ka3 = carea; }
            else if (kept == 4) { kb4 = cb; ka4 = carea; }
            else if (kept == 5) { kb5 = cb; ka5 = carea; }
            else if (kept == 6) { kb6 = cb; ka6 = carea; }
            else                { kb7 = cb; ka7 = carea; }
            kept++;
        }

        // consume: owning head dies; its chunk's floor = consumed (bv,bi)
        if (!dead && cn == bi) dead = true;
        if (l < HEADS && (bi >> 9) == mych) { fl_v = bv; fl_i = bi; }
        if (kept == MAXT) break;
    }

    if (l == 0) {
        for (int k = kept; k < MAXT; ++k) {
            int o = bc * KSEL + k;
            ws_msc[o] = NEGV;
            ws_box[o] = make_float4(0.f, 0.f, 0.f, 0.f);
        }
    }
}

// ---------------------------------------------------------------------------
// One block per batch: register-resident stable top-MAXT over C*K = 640 slots.
// (unchanged from R4 — validated)
// ---------------------------------------------------------------------------
__global__ __launch_bounds__(256) void topk_combine(
    const float* __restrict__ ws_msc,
    const float4* __restrict__ ws_box,
    float* __restrict__ out)
{
    __shared__ float red_val[2][4];
    __shared__ int   red_idx[2][4];

    const int b = blockIdx.x;
    const int tid = threadIdx.x;
    const float* msc = ws_msc + b * NCLS * KSEL;

    float v0 = (tid       < NCLS * KSEL) ? msc[tid]       : -INFINITY;
    float v1 = (tid + 256 < NCLS * KSEL) ? msc[tid + 256] : -INFINITY;
    float v2 = (tid + 512 < NCLS * KSEL) ? msc[tid + 512] : -INFINITY;

    const int OFF_SC = BATCH * MAXT * 4;
    const int OFF_CL = OFF_SC + BATCH * MAXT;
    const int OFF_VD = OFF_CL + BATCH * MAXT;

    int cnt = 0;
    int p = 0;
    #pragma unroll
    for (int t = 0; t < MAXT; ++t) {
        float bv = v0; int bi = tid;
        if (v1 > bv) { bv = v1; bi = tid + 256; }   // ascending i -> first max
        if (v2 > bv) { bv = v2; bi = tid + 512; }
        #pragma unroll
        for (int off = 32; off > 0; off >>= 1) {
            float ov = __shfl_down(bv, off, 64);
            int   oi = __shfl_down(bi, off, 64);
            if (ov > bv || (ov == bv && oi < bi)) { bv = ov; bi = oi; }
        }
        if ((tid & 63) == 0) { red_val[p][tid >> 6] = bv; red_idx[p][tid >> 6] = bi; }
        __syncthreads();
        bv = red_val[p][0]; bi = red_idx[p][0];
        #pragma unroll
        for (int w = 1; w < 4; ++w) {
            float ov = red_val[p][w]; int oi = red_idx[p][w];
            if (ov > bv || (ov == bv && oi < bi)) { bv = ov; bi = oi; }
        }
        p ^= 1;

        const bool valid = bv > SCORE_THR;
        cnt += valid ? 1 : 0;
        if (tid == t) {
            float4 bx = ws_box[b * NCLS * KSEL + bi];
            float* ob = out + ((size_t)b * MAXT + t) * 4;
            ob[0] = valid ? fminf(fmaxf(bx.x, 0.0f), 1.0f) : 0.0f;
            ob[1] = valid ? fminf(fmaxf(bx.y, 0.0f), 1.0f) : 0.0f;
            ob[2] = valid ? fminf(fmaxf(bx.z, 0.0f), 1.0f) : 0.0f;
            ob[3] = valid ? fminf(fmaxf(bx.w, 0.0f), 1.0f) : 0.0f;
            out[OFF_SC + b * MAXT + t] = valid ? bv : 0.0f;
            out[OFF_CL + b * MAXT + t] = valid ? (float)(bi >> 3) : 0.0f;
        }
        if (tid == (bi & 255)) {
            int w = bi >> 8;
            if (w == 0) v0 = -INFINITY;
            else if (w == 1) v1 = -INFINITY;
            else v2 = -INFINITY;
        }
    }
    if (tid == 0) out[OFF_VD + b] = (float)cnt;
}

extern "C" void kernel_launch(void* const* d_in, const int* in_sizes, int n_in,
                              void* d_out, int out_size, void* d_ws, size_t ws_size,
                              hipStream_t stream) {
    const float* boxes  = (const float*)d_in[0];   // (B, N, 1, 4)
    const float* scores = (const float*)d_in[1];   // (B, N, C)
    float* out = (float*)d_out;

    // ws layout: hv (B*C*80 f) | hn (B*C*80 i) | msc (B*C*K f) | box (B*C*K f4)
    const size_t nheads = (size_t)BATCH * NCLS * 2 * NSUB;       // 51200
    float* hv_g   = (float*)d_ws;
    int*   hn_g   = (int*)((char*)d_ws + nheads * 4);
    float* ws_msc = (float*)((char*)d_ws + nheads * 8);
    float4* ws_box = (float4*)((char*)d_ws + nheads * 8
                               + (size_t)BATCH * NCLS * KSEL * 4);

    class_heads<<<BATCH * NSUB, 320, 0, stream>>>(scores, hv_g, hn_g);
    nms_extract<<<BATCH * (NCLS / 4), 256, 0, stream>>>(hv_g, hn_g, scores,
                                                        boxes, ws_msc, ws_box);
    topk_combine<<<BATCH, 256, 0, stream>>>(ws_msc, ws_box, out);
}

// Round 8
// 49.916 us; speedup vs baseline: 1.7392x; 1.1011x over previous
//
#include <hip/hip_runtime.h>
#include <math.h>

#define BATCH 8
#define NBOX 10000
#define NCLS 80
#define KSEL 8
#define MAXT 8
#define IOU_THR 0.5f
#define SCORE_THR 0.5f
#define NEGV -1000000000.0f
#define IDXINF 0x7fffffff

#define SUBROWS 128         // rows per class_heads sub-chunk
#define NSUB 80             // 80*128 = 10240 >= 10000
#define NCHK 20             // phase-2 chunks of 512 rows (= 4 sub-chunks)
#define HEADS 40            // NCHK * 2 head lanes

// global candidate order: (val desc, idx asc) — matches jnp.argmax ties
__device__ __forceinline__ bool beats(float av, int an, float bv, int bn) {
    return (av > bv) || (av == bv && an < bn);
}

// u64 key: (float bits << 20) | (16383-idx) << 6 | lane. val > 0 => bit-monotone.
__device__ __forceinline__ unsigned long long packk(float v, int n, int lane) {
    return ((unsigned long long)__float_as_uint(v) << 20)
         | ((unsigned long long)(16383 - n) << 6)
         | (unsigned long long)lane;
}

// threshold + top-2 update (ascending n -> first-idx ties)
#define T2C(V1, I1, V2, I2, X, N)                                           \
    do {                                                                    \
        float _x = ((X) > SCORE_THR) ? (X) : NEGV;                          \
        if (_x > (V1)) { (V2)=(V1); (I2)=(I1); (V1)=_x; (I1)=(N); }         \
        else if (_x > (V2)) { (V2)=_x; (I2)=(N); }                          \
    } while (0)

// merge sorted pair (A1>=A2) into running sorted (h1,j1)>=(h2,j2)
#define MRG(A1, A1N, A2, A2N)                                               \
    do {                                                                    \
        if (beats((A1), (A1N), h1, j1)) {                                   \
            float _t = h1; int _tn = j1;                                    \
            h1 = (A1); j1 = (A1N);                                          \
            if (beats((A2), (A2N), _t, _tn)) { h2 = (A2); j2 = (A2N); }     \
            else                             { h2 = _t;  j2 = _tn;  }       \
        } else if (beats((A1), (A1N), h2, j2)) { h2 = (A1); j2 = (A1N); }   \
    } while (0)

// IoU suppression test, per-op IEEE rounding identical to numpy reference;
// union order = kept_area + cand_area.
#define IOU_SUP(KB, KA)                                                     \
    do {                                                                    \
        float ih = fmaxf(__fsub_rn(fminf((KB).z, cb.z), fmaxf((KB).x, cb.x)), 0.0f); \
        float iw = fmaxf(__fsub_rn(fminf((KB).w, cb.w), fmaxf((KB).y, cb.y)), 0.0f); \
        float inter = __fmul_rn(ih, iw);                                    \
        float uni   = __fsub_rn(__fadd_rn((KA), carea), inter);             \
        float iou   = __fdiv_rn(inter, fmaxf(uni, 1e-9f));                  \
        if (iou > IOU_THR) sup = true;                                      \
    } while (0)

// rescan eligibility: strictly below floor (xv,xi); keep max in beats-order
#define ELG(X, N)                                                           \
    do {                                                                    \
        if (((X) < xv || ((X) == xv && (N) > xi)) &&                        \
            ((X) > nv || ((X) == nv && (N) < nn))) { nv = (X); nn = (N); }  \
    } while (0)

__device__ __forceinline__ float aload(const float* p) {
    return __hip_atomic_load(p, __ATOMIC_RELAXED, __HIP_MEMORY_SCOPE_AGENT);
}

// ---------------------------------------------------------------------------
// Kernel A: per-(batch, 128-row sub-chunk) top-2 heads for all 80 classes.
// Reads raw (B,N,C) once, coalesced float4 across classes. 640 blocks for
// load-latency hiding. Thread = (q,g): classes 4q..4q+3, rows g*8..g*8+7.
// Also zeroes the per-batch completion counters (block 0).
// ---------------------------------------------------------------------------
__global__ __launch_bounds__(320) void class_heads(
    const float* __restrict__ scores,   // (B, N, C)
    float* __restrict__ hv_g,           // (B*C, 2*NSUB)
    int*   __restrict__ hn_g,
    int*   __restrict__ cnt)            // (BATCH) completion counters
{
    __shared__ float lv[16][NCLS][2];   // 10.2 KB
    __shared__ int   ln[16][NCLS][2];   // 10.2 KB

    const int bid = blockIdx.x;         // b + 8*sub -> XCD pin
    const int b   = bid & 7;
    const int sub = bid >> 3;
    const int n0  = sub * SUBROWS;
    const int tid = threadIdx.x;
    const int q   = tid % 20;           // class quad
    const int g   = tid / 20;           // row group [0,16)

    if (bid == 0 && tid < BATCH) cnt[tid] = 0;   // visible at kernel boundary

    const float* base = scores + ((size_t)b * NBOX + n0) * NCLS + 4 * q;

    float v10 = NEGV, v20 = NEGV, v11 = NEGV, v21 = NEGV;
    float v12 = NEGV, v22 = NEGV, v13 = NEGV, v23 = NEGV;
    int   i10 = IDXINF, i20 = IDXINF, i11 = IDXINF, i21 = IDXINF;
    int   i12 = IDXINF, i22 = IDXINF, i13 = IDXINF, i23 = IDXINF;

    #pragma unroll
    for (int k = 0; k < 8; ++k) {
        const int r = g * 8 + k;
        const int n = n0 + r;
        if (n < NBOX) {
            float4 x = *(const float4*)(base + (size_t)r * NCLS);
            T2C(v10, i10, v20, i20, x.x, n);
            T2C(v11, i11, v21, i21, x.y, n);
            T2C(v12, i12, v22, i22, x.z, n);
            T2C(v13, i13, v23, i23, x.w, n);
        }
    }

    const int c0 = 4 * q;
    lv[g][c0 + 0][0] = v10; lv[g][c0 + 0][1] = v20;
    lv[g][c0 + 1][0] = v11; lv[g][c0 + 1][1] = v21;
    lv[g][c0 + 2][0] = v12; lv[g][c0 + 2][1] = v22;
    lv[g][c0 + 3][0] = v13; lv[g][c0 + 3][1] = v23;
    ln[g][c0 + 0][0] = i10; ln[g][c0 + 0][1] = i20;
    ln[g][c0 + 1][0] = i11; ln[g][c0 + 1][1] = i21;
    ln[g][c0 + 2][0] = i12; ln[g][c0 + 2][1] = i22;
    ln[g][c0 + 3][0] = i13; ln[g][c0 + 3][1] = i23;
    __syncthreads();

    if (tid < NCLS) {
        const int c = tid;
        float h1 = NEGV, h2 = NEGV;
        int   j1 = IDXINF, j2 = IDXINF;
        #pragma unroll
        for (int g2 = 0; g2 < 16; ++g2) {    // ascending g2 = ascending n
            float a1 = lv[g2][c][0], a2 = lv[g2][c][1];
            int  a1n = ln[g2][c][0], a2n = ln[g2][c][1];
            MRG(a1, a1n, a2, a2n);
        }
        const size_t o = ((size_t)(b * NCLS + c)) * (2 * NSUB) + 2 * sub;
        hv_g[o] = h1; hv_g[o + 1] = h2;
        hn_g[o] = j1; hn_g[o + 1] = j2;
    }
}

// ---------------------------------------------------------------------------
// Kernel B: one WAVE per class (4 waves/block). Heads+boxes in registers;
// per round ONE fused u64-key butterfly (live max + blind-floor max),
// winner box via lane shuffles, IoU vs kept in named registers.
// Last block per batch (atomic election) runs the batch's top-8 combine.
// ---------------------------------------------------------------------------
__global__ __launch_bounds__(256) void nms_extract(
    const float* __restrict__ hv_g,
    const int*   __restrict__ hn_g,
    const float* __restrict__ scores,   // raw (B,N,C)
    const float* __restrict__ boxes,    // (B,N,4)
    float* __restrict__ ws_msc,
    float* __restrict__ ws_box,         // (B*C*K, 4) floats
    int*   __restrict__ cnt,
    float* __restrict__ out)
{
    __shared__ float rv[2][4];
    __shared__ int   ri[2][4];
    __shared__ int   s_old;

    const int bid = blockIdx.x;         // b + 8*grp -> XCD pin
    const int b   = bid & 7;
    const int grp = bid >> 3;
    const int w   = threadIdx.x >> 6;
    const int l   = threadIdx.x & 63;
    const int tid = threadIdx.x;
    const int c   = grp * 4 + w;
    const int bc  = b * NCLS + c;

    const float*  raw  = scores + (size_t)b * NBOX * NCLS + c;
    const float4* box4 = (const float4*)(boxes + (size_t)b * NBOX * 4);

    // ---- head init: chunk ch = l>>1 covers subs 4ch..4ch+3 (offs 8ch..8ch+7)
    float cv = NEGV; int cn = IDXINF;
    bool dead = (l >= HEADS);
    if (l < HEADS) {
        const int ch = l >> 1;
        const size_t o = (size_t)bc * (2 * NSUB) + 8 * ch;
        float4 av0 = *(const float4*)(hv_g + o);
        float4 av1 = *(const float4*)(hv_g + o + 4);
        int4   an0 = *(const int4*)  (hn_g + o);
        int4   an1 = *(const int4*)  (hn_g + o + 4);
        float h1 = av0.x, h2 = av0.y;
        int   j1 = an0.x, j2 = an0.y;
        MRG(av0.z, an0.z, av0.w, an0.w);
        MRG(av1.x, an1.x, av1.y, an1.y);
        MRG(av1.z, an1.z, av1.w, an1.w);
        cv = (l & 1) ? h2 : h1;
        cn = (l & 1) ? j2 : j1;
        if (!(cv > SCORE_THR)) dead = true;
    }
    // per-head box prefetch (off critical path of rounds)
    float4 bx = make_float4(0.f, 0.f, 0.f, 0.f);
    float  barea = 0.f;
    if (!dead) {
        bx = box4[cn];
        barea = __fmul_rn(__fsub_rn(bx.z, bx.x), __fsub_rn(bx.w, bx.y));
    }

    float fl_v = NEGV; int fl_i = IDXINF;
    const int mych = l >> 1;

    float4 kb0, kb1, kb2, kb3, kb4, kb5, kb6, kb7;
    float  ka0=0, ka1=0, ka2=0, ka3=0, ka4=0, ka5=0, ka6=0, ka7=0;
    kb0 = kb1 = kb2 = kb3 = kb4 = kb5 = kb6 = kb7 = make_float4(0, 0, 0, 0);
    int kept = 0;

    for (;;) {
        const unsigned long long db = __ballot(dead);
        const bool blind = (l < HEADS) && (((db >> (2 * mych)) & 3ull) == 3ull);
        unsigned long long lk = dead ? 0ull : packk(cv, cn, l);
        unsigned long long fk = (blind && fl_v > SCORE_THR)
                              ? packk(fl_v, fl_i, 0) : 0ull;
        #pragma unroll
        for (int off = 1; off < 64; off <<= 1) {
            unsigned long long ol = __shfl_xor(lk, off, 64);
            unsigned long long of = __shfl_xor(fk, off, 64);
            if (ol > lk) lk = ol;
            if (of > fk) fk = of;
        }
        if (fk > lk) {
            // exact rescan of the blind chunk: max strictly below floor (xv,xi)
            const int xi = 16383 - (int)((fk >> 6) & 0x3FFF);
            const float xv = __uint_as_float((unsigned)(fk >> 20));
            const int chr = xi >> 9;
            const int nb  = chr << 9;
            float nv = NEGV; int nn = IDXINF;
            #pragma unroll
            for (int qq = 0; qq < 8; ++qq) {
                const int n = nb + qq * 64 + l;
                float x = NEGV;
                if (n < NBOX) {
                    float t = raw[(size_t)n * NCLS];
                    x = (t > SCORE_THR) ? t : NEGV;
                }
                ELG(x, n);
            }
            #pragma unroll
            for (int off = 1; off < 64; off <<= 1) {
                float ov = __shfl_xor(nv, off, 64);
                int   oi = __shfl_xor(nn, off, 64);
                if (beats(ov, oi, nv, nn)) { nv = ov; nn = oi; }
            }
            if (l == 2 * chr) {
                cv = nv; cn = nn;
                dead = !(nv > SCORE_THR);
                if (!dead) {
                    bx = box4[cn];
                    barea = __fmul_rn(__fsub_rn(bx.z, bx.x), __fsub_rn(bx.w, bx.y));
                }
            }
            continue;
        }
        if (lk == 0ull) break;

        const int   owner = (int)(lk & 63ull);
        const int   bi    = 16383 - (int)((lk >> 6) & 0x3FFF);
        const float bv    = __uint_as_float((unsigned)(lk >> 20));
        float4 cb;
        cb.x = __shfl(bx.x, owner, 64);
        cb.y = __shfl(bx.y, owner, 64);
        cb.z = __shfl(bx.z, owner, 64);
        cb.w = __shfl(bx.w, owner, 64);
        const float carea = __shfl(barea, owner, 64);

        bool sup = false;
        if (kept > 0) IOU_SUP(kb0, ka0);
        if (kept > 1) IOU_SUP(kb1, ka1);
        if (kept > 2) IOU_SUP(kb2, ka2);
        if (kept > 3) IOU_SUP(kb3, ka3);
        if (kept > 4) IOU_SUP(kb4, ka4);
        if (kept > 5) IOU_SUP(kb5, ka5);
        if (kept > 6) IOU_SUP(kb6, ka6);
        if (kept > 7) IOU_SUP(kb7, ka7);

        if (!sup) {
            if (l == 0) {
                const int o = bc * KSEL + kept;
                ws_msc[o] = bv;
                float* ob = ws_box + (size_t)o * 4;
                ob[0] = cb.x; ob[1] = cb.y; ob[2] = cb.z; ob[3] = cb.w;
            }
            if      (kept == 0) { kb0 = cb; ka0 = carea; }
            else if (kept == 1) { kb1 = cb; ka1 = carea; }
            else if (kept == 2) { kb2 = cb; ka2 = carea; }
            else if (kept == 3) { kb3 = cb; ka3 = carea; }
            else if (kept == 4) { kb4 = cb; ka4 = carea; }
            else if (kept == 5) { kb5 = cb; ka5 = carea; }
            else if (kept == 6) { kb6 = cb; ka6 = carea; }
            else                { kb7 = cb; ka7 = carea; }
            kept++;
        }

        if (l == owner) dead = true;
        if (l < HEADS && (bi >> 9) == mych) { fl_v = bv; fl_i = bi; }
        if (kept == MAXT) break;
    }

    if (l == 0) {
        for (int k = kept; k < MAXT; ++k) {
            const int o = bc * KSEL + k;
            ws_msc[o] = NEGV;
            float* ob = ws_box + (size_t)o * 4;
            ob[0] = 0.f; ob[1] = 0.f; ob[2] = 0.f; ob[3] = 0.f;
        }
    }

    // ---- last-block election for this batch -> fused top-8 combine ----
    __syncthreads();
    if (tid == 0) {
        __threadfence();
        s_old = atomicAdd(&cnt[b], 1);
    }
    __syncthreads();
    if (s_old != (NCLS / 4) - 1) return;
    __threadfence();

    const float* msc = ws_msc + b * NCLS * KSEL;
    float v0 = aload(msc + tid);
    float v1 = aload(msc + tid + 256);
    float v2 = (tid + 512 < NCLS * KSEL) ? aload(msc + tid + 512) : -INFINITY;

    const int OFF_SC = BATCH * MAXT * 4;
    const int OFF_CL = OFF_SC + BATCH * MAXT;
    const int OFF_VD = OFF_CL + BATCH * MAXT;

    int tot = 0;
    int p = 0;
    #pragma unroll
    for (int t = 0; t < MAXT; ++t) {
        float bv = v0; int bi = tid;
        if (v1 > bv) { bv = v1; bi = tid + 256; }   // ascending i -> first max
        if (v2 > bv) { bv = v2; bi = tid + 512; }
        #pragma unroll
        for (int off = 32; off > 0; off >>= 1) {
            float ov = __shfl_down(bv, off, 64);
            int   oi = __shfl_down(bi, off, 64);
            if (ov > bv || (ov == bv && oi < bi)) { bv = ov; bi = oi; }
        }
        if ((tid & 63) == 0) { rv[p][tid >> 6] = bv; ri[p][tid >> 6] = bi; }
        __syncthreads();
        bv = rv[p][0]; bi = ri[p][0];
        #pragma unroll
        for (int w2 = 1; w2 < 4; ++w2) {
            float ov = rv[p][w2]; int oi = ri[p][w2];
            if (ov > bv || (ov == bv && oi < bi)) { bv = ov; bi = oi; }
        }
        p ^= 1;

        const bool valid = bv > SCORE_THR;
        tot += valid ? 1 : 0;
        if (tid == t) {
            const float* sb = ws_box + ((size_t)b * NCLS * KSEL + bi) * 4;
            float bx0 = aload(sb + 0), bx1 = aload(sb + 1);
            float bx2 = aload(sb + 2), bx3 = aload(sb + 3);
            float* ob = out + ((size_t)b * MAXT + t) * 4;
            ob[0] = valid ? fminf(fmaxf(bx0, 0.0f), 1.0f) : 0.0f;
            ob[1] = valid ? fminf(fmaxf(bx1, 0.0f), 1.0f) : 0.0f;
            ob[2] = valid ? fminf(fmaxf(bx2, 0.0f), 1.0f) : 0.0f;
            ob[3] = valid ? fminf(fmaxf(bx3, 0.0f), 1.0f) : 0.0f;
            out[OFF_SC + b * MAXT + t] = valid ? bv : 0.0f;
            out[OFF_CL + b * MAXT + t] = valid ? (float)(bi >> 3) : 0.0f;
        }
        if (tid == (bi & 255)) {
            int w2 = bi >> 8;
            if (w2 == 0) v0 = -INFINITY;
            else if (w2 == 1) v1 = -INFINITY;
            else v2 = -INFINITY;
        }
    }
    if (tid == 0) out[OFF_VD + b] = (float)tot;
}

extern "C" void kernel_launch(void* const* d_in, const int* in_sizes, int n_in,
                              void* d_out, int out_size, void* d_ws, size_t ws_size,
                              hipStream_t stream) {
    const float* boxes  = (const float*)d_in[0];   // (B, N, 1, 4)
    const float* scores = (const float*)d_in[1];   // (B, N, C)
    float* out = (float*)d_out;

    // ws layout: hv | hn | msc | box | cnt
    const size_t nheads = (size_t)BATCH * NCLS * 2 * NSUB;       // 102400
    char* p = (char*)d_ws;
    float* hv_g   = (float*)p;                     p += nheads * 4;
    int*   hn_g   = (int*)p;                       p += nheads * 4;
    float* ws_msc = (float*)p;                     p += (size_t)BATCH * NCLS * KSEL * 4;
    float* ws_box = (float*)p;                     p += (size_t)BATCH * NCLS * KSEL * 16;
    int*   cnt    = (int*)p;

    class_heads<<<BATCH * NSUB, 320, 0, stream>>>(scores, hv_g, hn_g, cnt);
    nms_extract<<<BATCH * (NCLS / 4), 256, 0, stream>>>(hv_g, hn_g, scores,
                                                        boxes, ws_msc, ws_box,
                                                        cnt, out);
}